// Round 6
// baseline (749.859 us; speedup 1.0000x reference)
//
#include <hip/hip_runtime.h>
#include <stdint.h>

#define NN 50000
#define NE 800000
#define HID 128
#define NG 500
#define NL 7

typedef short bf16x8 __attribute__((ext_vector_type(8)));
typedef float f32x4 __attribute__((ext_vector_type(4)));

typedef __attribute__((address_space(1))) const unsigned int ga_u32;
typedef __attribute__((address_space(3))) unsigned int ls_u32;

__device__ __forceinline__ unsigned short f2bf(float f) {
  unsigned int u = __builtin_bit_cast(unsigned int, f);
  u += 0x7FFFu + ((u >> 16) & 1u);
  return (unsigned short)(u >> 16);
}
__device__ __forceinline__ float bf2f(unsigned short h) {
  unsigned int u = ((unsigned int)h) << 16;
  return __builtin_bit_cast(float, u);
}
__device__ __forceinline__ float bflo(unsigned int u) {
  return __builtin_bit_cast(float, u << 16);
}
__device__ __forceinline__ float bfhi(unsigned int u) {
  return __builtin_bit_cast(float, u & 0xffff0000u);
}

// ---- fused preprocessing: cvt + pad + degree histogram + weight swizzle ----
__global__ void k_pre(const float* __restrict__ x, unsigned short* __restrict__ hA,
                      unsigned short* __restrict__ hB,
                      const int* __restrict__ dstE, int* __restrict__ deg,
                      const float* __restrict__ Wl, const float* __restrict__ Wr,
                      unsigned short* __restrict__ wswh,
                      unsigned short* __restrict__ wswl) {
  int i = blockIdx.x * 256 + threadIdx.x;
  if (i < NN * HID / 4) {
    float4 v = ((const float4*)x)[i];
    ushort4 r;
    r.x = f2bf(v.x); r.y = f2bf(v.y); r.z = f2bf(v.z); r.w = f2bf(v.w);
    ((ushort4*)hA)[i] = r;
  }
  if (i < NE) atomicAdd(&deg[dstE[i]], 1);
  if (i < NL * 2 * 4 * 4096) {
    int j = i & 7, ii = (i >> 3) & 15, q = (i >> 7) & 3, t = (i >> 9) & 7;
    int cc = (i >> 12) & 3, m = (i >> 14) & 1, l = i >> 15;
    int k = cc * 32 + q * 8 + j, n = t * 16 + ii;
    const float* W = m ? Wr : Wl;
    float w = W[l * HID * HID + k * HID + n];
    unsigned short hi = f2bf(w);
    unsigned short lo = f2bf(w - bf2f(hi));
    wswh[i] = hi;
    wswl[i] = lo;
  }
  if (i < 32) {  // zero pad row NN of both h buffers
    unsigned short* pad = (i < 16) ? (hA + (size_t)NN * HID) : (hB + (size_t)NN * HID);
    *(uint4*)&pad[(i & 15) * 8] = make_uint4(0u, 0u, 0u, 0u);
  }
}

// ---- exclusive scan (3 kernels) ----
__global__ void k_scan1(const int* __restrict__ deg, int* __restrict__ offs,
                        int* __restrict__ bsum) {
  int i = blockIdx.x * 256 + threadIdx.x;
  int v = (i < NN) ? deg[i] : 0;
  int lane = threadIdx.x & 63, wv = threadIdx.x >> 6;
  int x = v;
  #pragma unroll
  for (int d = 1; d < 64; d <<= 1) {
    int y = __shfl_up(x, d, 64);
    if (lane >= d) x += y;
  }
  __shared__ int wsum[4];
  if (lane == 63) wsum[wv] = x;
  __syncthreads();
  if (threadIdx.x == 0) {
    int s = 0;
    for (int k = 0; k < 4; k++) { int t = wsum[k]; wsum[k] = s; s += t; }
    bsum[blockIdx.x] = s;
  }
  __syncthreads();
  if (i < NN) offs[i] = x - v + wsum[wv];
}

__global__ void k_scan2(int* __restrict__ bsum, int nb) {
  int i = threadIdx.x;
  int v = (i < nb) ? bsum[i] : 0;
  int lane = threadIdx.x & 63, wv = threadIdx.x >> 6;
  int x = v;
  #pragma unroll
  for (int d = 1; d < 64; d <<= 1) {
    int y = __shfl_up(x, d, 64);
    if (lane >= d) x += y;
  }
  __shared__ int wsum[4];
  if (lane == 63) wsum[wv] = x;
  __syncthreads();
  if (threadIdx.x == 0) {
    int s = 0;
    for (int k = 0; k < 4; k++) { int t = wsum[k]; wsum[k] = s; s += t; }
  }
  __syncthreads();
  if (i < nb) bsum[i] = x - v + wsum[wv];
}

__global__ void k_scan3(const int* __restrict__ deg, int* __restrict__ offs,
                        const int* __restrict__ bsum, float* __restrict__ invd) {
  int i = blockIdx.x * 256 + threadIdx.x;
  if (i < NN) {
    offs[i] += bsum[blockIdx.x];
    int d = deg[i];
    invd[i] = 1.0f / (float)(d > 0 ? d : 1);
    if (i == 0) offs[NN] = NE;
  }
}

// ---- CSR fill ----
__global__ void k_fill(const int* __restrict__ src, const int* __restrict__ dst,
                       const int* __restrict__ offs, int* __restrict__ cur,
                       int* __restrict__ csr) {
  int e = blockIdx.x * 256 + threadIdx.x;
  if (e < NE) {
    int d = dst[e];
    int p = atomicAdd(&cur[d], 1);
    csr[offs[d] + p] = src[e];
  }
}

// stage 4 neighbor rows (strip st) into LDS slot via async global_load_lds
__device__ __forceinline__ void stage_rows(const unsigned short* __restrict__ curh,
                                           unsigned short* slotp, int idx, int st,
                                           int lane) {
  int row = __shfl(idx, st * 4 + (lane >> 4));
  const unsigned short* g = curh + (size_t)row * HID + (lane & 15) * 8;
  __builtin_amdgcn_global_load_lds((ga_u32*)g, (ls_u32*)slotp, 16, 0, 0);
}

__device__ __forceinline__ void acc_slot(const unsigned int* stageU, int slot,
                                         int lane, float& ax, float& ay) {
  #pragma unroll
  for (int p = 0; p < 4; ++p) {
    unsigned int v = stageU[slot * 256 + p * 64 + lane];
    ax += bflo(v); ay += bfhi(v);
  }
}

// ---- fused SAGE layer: async-LDS gather + MFMA GEMM ----
__global__ __launch_bounds__(256) void k_layer(const unsigned short* __restrict__ curh,
                                               const int* __restrict__ offs,
                                               const int* __restrict__ csr,
                                               const float* __restrict__ invd,
                                               const unsigned short* __restrict__ wswh,
                                               const unsigned short* __restrict__ wswl,
                                               const float* __restrict__ bias,
                                               unsigned short* __restrict__ out,
                                               int relu) {
  __shared__ __align__(16) unsigned short sA[64 * 136];  // agg (bf16)
  __shared__ __align__(16) unsigned short sH[64 * 136];  // root
  // 16 KB region: gather staging (4 KB/wave, 4 slots x 4 rows x 256 B),
  // later re-used as Whi (shorts 0..4095) | Wlo (shorts 4096..8191)
  __shared__ __align__(16) unsigned short sW2[8192];
  const int tid = threadIdx.x;
  const int lane = tid & 63, wv = tid >> 6;
  const int row0 = blockIdx.x * 64;

  // stage root rows: 64 rows x 16 uint4
  #pragma unroll
  for (int it = 0; it < 4; ++it) {
    int ch = tid + it * 256;
    int r = ch >> 4, u4 = ch & 15;
    int row = row0 + r;
    uint4 v = make_uint4(0u, 0u, 0u, 0u);
    if (row < NN) v = ((const uint4*)(curh + (size_t)row * HID))[u4];
    *(uint4*)&sH[r * 136 + u4 * 8] = v;
  }

  // ---- gather: full wave per node, async staging, vmcnt-pipelined ----
  unsigned short* stage = sW2 + wv * 2048;
  const unsigned int* stageU = (const unsigned int*)stage;
  for (int rr = 0; rr < 16; ++rr) {
    int node = row0 + (wv << 4) + rr;
    float ax = 0.f, ay = 0.f;
    if (node < NN) {
      float sc = invd[node];
      int s = offs[node], eE = offs[node + 1];
      for (int base = s; base < eE; base += 64) {
        __builtin_amdgcn_sched_barrier(0);
        int m = eE - base; if (m > 64) m = 64;
        int idx = (lane < m) ? csr[base + lane] : NN;  // pad row NN = zeros
        int nst = (m + 3) >> 2;
        stage_rows(curh, stage + 0 * 512, idx, 0, lane);
        if (nst > 1) stage_rows(curh, stage + 1 * 512, idx, 1, lane);
        if (nst > 2) stage_rows(curh, stage + 2 * 512, idx, 2, lane);
        if (nst > 3) stage_rows(curh, stage + 3 * 512, idx, 3, lane);
        int st = 0;
        for (; st + 4 < nst; ++st) {
          __builtin_amdgcn_s_waitcnt(0x0F70 | 3);
          acc_slot(stageU, st & 3, lane, ax, ay);
          __builtin_amdgcn_sched_barrier(0);
          stage_rows(curh, stage + (st & 3) * 512, idx, st + 4, lane);
        }
        int rem = nst - st;
        if (rem >= 4) { __builtin_amdgcn_s_waitcnt(0x0F70 | 3);
                        acc_slot(stageU, st & 3, lane, ax, ay); ++st; }
        if (rem >= 3) { __builtin_amdgcn_s_waitcnt(0x0F70 | 2);
                        acc_slot(stageU, st & 3, lane, ax, ay); ++st; }
        if (rem >= 2) { __builtin_amdgcn_s_waitcnt(0x0F70 | 1);
                        acc_slot(stageU, st & 3, lane, ax, ay); ++st; }
        __builtin_amdgcn_s_waitcnt(0x0F70);
        acc_slot(stageU, st & 3, lane, ax, ay);
        __builtin_amdgcn_sched_barrier(0);
      }
      ax *= sc; ay *= sc;
    }
    *(unsigned int*)&sA[((wv << 4) + rr) * 136 + lane * 2] =
        (unsigned int)f2bf(ax) | ((unsigned int)f2bf(ay) << 16);
  }
  __syncthreads();

  // ---- GEMM: out = relu?( sA@Wl + bl + sH@Wr ), W in hi/lo bf16 planes ----
  f32x4 acc[8];
  #pragma unroll
  for (int t = 0; t < 8; t++) acc[t] = (f32x4){0.f, 0.f, 0.f, 0.f};
  const int mr = (wv << 4) + (lane & 15);
  const int q = lane >> 4;

  for (int c = 0; c < 8; ++c) {
    const uint4* wh = (const uint4*)(wswh + c * 4096);
    const uint4* wl = (const uint4*)(wswl + c * 4096);
    ((uint4*)sW2)[tid] = wh[tid];
    ((uint4*)sW2)[tid + 256] = wh[tid + 256];
    ((uint4*)sW2)[tid + 512] = wl[tid];
    ((uint4*)sW2)[tid + 768] = wl[tid + 256];
    __syncthreads();
    const unsigned short* sSrc = (c < 4) ? sA : sH;
    bf16x8 a = *(const bf16x8*)&sSrc[mr * 136 + (c & 3) * 32 + q * 8];
    #pragma unroll
    for (int t = 0; t < 8; t++) {
      bf16x8 bh = *(const bf16x8*)&sW2[(t * 4 + q) * 128 + (lane & 15) * 8];
      bf16x8 bl2 = *(const bf16x8*)&sW2[4096 + (t * 4 + q) * 128 + (lane & 15) * 8];
      acc[t] = __builtin_amdgcn_mfma_f32_16x16x32_bf16(a, bh, acc[t], 0, 0, 0);
      acc[t] = __builtin_amdgcn_mfma_f32_16x16x32_bf16(a, bl2, acc[t], 0, 0, 0);
    }
    __syncthreads();
  }

  const int ci = lane & 15;
  const int rb = (wv << 4) + (lane >> 4) * 4;
  #pragma unroll
  for (int t = 0; t < 8; t++) {
    int n = t * 16 + ci;
    float bn = bias[n];
    #pragma unroll
    for (int r2 = 0; r2 < 4; r2++) {
      int row = row0 + rb + r2;
      if (row < NN) {
        float v = acc[t][r2] + bn;
        if (relu) v = fmaxf(v, 0.f);
        out[(size_t)row * HID + n] = f2bf(v);
      }
    }
  }
}

// ---- global add pool (batch sorted -> binary search, no atomics) ----
__global__ void k_pool(const unsigned short* __restrict__ h,
                       const int* __restrict__ batch, float* __restrict__ pooled) {
  int g = blockIdx.x;
  __shared__ int rng[2];
  if (threadIdx.x < 2) {
    int target = g + threadIdx.x;
    int lo = 0, hi = NN;
    while (lo < hi) {
      int mid = (lo + hi) >> 1;
      if (batch[mid] < target) lo = mid + 1; else hi = mid;
    }
    rng[threadIdx.x] = lo;
  }
  __syncthreads();
  int s = rng[0], e = rng[1];
  float a = 0.f;
  for (int r = s; r < e; ++r) a += bf2f(h[(size_t)r * HID + threadIdx.x]);
  pooled[g * HID + threadIdx.x] = a;
}

// ---- final projection 128 -> 2 (all fp32) ----
__global__ void k_out(const float* __restrict__ pooled,
                      const float* __restrict__ Wout,
                      const float* __restrict__ bout,
                      float* __restrict__ out) {
  int g = blockIdx.x;
  int l = threadIdx.x;  // 64
  float a = pooled[g * HID + l], b = pooled[g * HID + 64 + l];
  float p0 = a * Wout[l * 2] + b * Wout[(l + 64) * 2];
  float p1 = a * Wout[l * 2 + 1] + b * Wout[(l + 64) * 2 + 1];
  #pragma unroll
  for (int d = 32; d; d >>= 1) {
    p0 += __shfl_down(p0, d, 64);
    p1 += __shfl_down(p1, d, 64);
  }
  if (l == 0) {
    out[g * 2] = p0 + bout[0];
    out[g * 2 + 1] = p1 + bout[1];
  }
}

extern "C" void kernel_launch(void* const* d_in, const int* in_sizes, int n_in,
                              void* d_out, int out_size, void* d_ws, size_t ws_size,
                              hipStream_t stream) {
  const float* x = (const float*)d_in[0];
  const int* ei = (const int*)d_in[1];
  const int* batch = (const int*)d_in[2];
  const float* Wl = (const float*)d_in[3];
  const float* Wr = (const float*)d_in[4];
  const float* bl = (const float*)d_in[5];
  const float* Wout = (const float*)d_in[6];
  const float* bout = (const float*)d_in[7];
  float* out = (float*)d_out;
  const int* srcE = ei;
  const int* dstE = ei + NE;

  // workspace layout (~31.6 MB total); h buffers have a zero pad row NN
  char* w = (char*)d_ws;
  unsigned short* hA = (unsigned short*)w; w += (size_t)(NN + 1) * HID * 2;
  unsigned short* hB = (unsigned short*)w; w += (size_t)(NN + 1) * HID * 2;
  float* invd = (float*)w;   w += (size_t)NN * 4;
  float* pooled = (float*)w; w += (size_t)NG * HID * 4;
  int* deg = (int*)w;  w += (size_t)NN * 4;
  int* cur = (int*)w;  w += (size_t)NN * 4;      // adjacent to deg (one memset)
  int* offs = (int*)w; w += (size_t)50004 * 4;
  int* csr = (int*)w;  w += (size_t)NE * 4;
  int* bsum = (int*)w; w += 256 * 4;
  unsigned short* wswh = (unsigned short*)w; w += (size_t)NL * 2 * 4 * 4096 * 2;
  unsigned short* wswl = (unsigned short*)w;

  hipMemsetAsync(deg, 0, (size_t)NN * 2 * 4, stream);
  k_pre<<<(NN * HID / 4 + 255) / 256, 256, 0, stream>>>(x, hA, hB, dstE, deg,
                                                        Wl, Wr, wswh, wswl);
  int nb = (NN + 255) / 256;
  k_scan1<<<nb, 256, 0, stream>>>(deg, offs, bsum);
  k_scan2<<<1, 256, 0, stream>>>(bsum, nb);
  k_scan3<<<nb, 256, 0, stream>>>(deg, offs, bsum, invd);
  k_fill<<<(NE + 255) / 256, 256, 0, stream>>>(srcE, dstE, offs, cur, csr);

  unsigned short* curh = hA;
  unsigned short* nxth = hB;
  for (int l = 0; l < NL; l++) {
    k_layer<<<(NN + 63) / 64, 256, 0, stream>>>(curh, offs, csr, invd,
                                                wswh + (size_t)l * 2 * 4 * 4096,
                                                wswl + (size_t)l * 2 * 4 * 4096,
                                                bl + l * HID, nxth,
                                                (l < NL - 1) ? 1 : 0);
    unsigned short* t = curh; curh = nxth; nxth = t;
  }
  k_pool<<<NG, 128, 0, stream>>>(curh, batch, pooled);
  k_out<<<NG, 64, 0, stream>>>(pooled, Wout, bout, out);
}

// Round 7
// 539.266 us; speedup vs baseline: 1.3905x; 1.3905x over previous
//
#include <hip/hip_runtime.h>
#include <stdint.h>

#define NN 50000
#define NE 800000
#define HID 128
#define NG 500
#define NL 7

typedef short bf16x8 __attribute__((ext_vector_type(8)));
typedef float f32x4 __attribute__((ext_vector_type(4)));

__device__ __forceinline__ unsigned short f2bf(float f) {
  unsigned int u = __builtin_bit_cast(unsigned int, f);
  u += 0x7FFFu + ((u >> 16) & 1u);
  return (unsigned short)(u >> 16);
}
__device__ __forceinline__ float bf2f(unsigned short h) {
  unsigned int u = ((unsigned int)h) << 16;
  return __builtin_bit_cast(float, u);
}
__device__ __forceinline__ float bflo(unsigned int u) {
  return __builtin_bit_cast(float, u << 16);
}
__device__ __forceinline__ float bfhi(unsigned int u) {
  return __builtin_bit_cast(float, u & 0xffff0000u);
}

// ---- fused preprocessing: cvt + pad rows + degree histogram + weight swizzle ----
__global__ void k_pre(const float* __restrict__ x, unsigned short* __restrict__ hA,
                      unsigned short* __restrict__ hB,
                      const int* __restrict__ dstE, int* __restrict__ deg,
                      const float* __restrict__ Wl, const float* __restrict__ Wr,
                      unsigned short* __restrict__ wswh,
                      unsigned short* __restrict__ wswl) {
  int i = blockIdx.x * 256 + threadIdx.x;
  if (i < NN * HID / 4) {
    float4 v = ((const float4*)x)[i];
    ushort4 r;
    r.x = f2bf(v.x); r.y = f2bf(v.y); r.z = f2bf(v.z); r.w = f2bf(v.w);
    ((ushort4*)hA)[i] = r;
  }
  if (i < NE) atomicAdd(&deg[dstE[i]], 1);
  if (i < NL * 2 * 4 * 4096) {
    int j = i & 7, ii = (i >> 3) & 15, q = (i >> 7) & 3, t = (i >> 9) & 7;
    int cc = (i >> 12) & 3, m = (i >> 14) & 1, l = i >> 15;
    int k = cc * 32 + q * 8 + j, n = t * 16 + ii;
    const float* W = m ? Wr : Wl;
    float w = W[l * HID * HID + k * HID + n];
    unsigned short hi = f2bf(w);
    unsigned short lo = f2bf(w - bf2f(hi));
    wswh[i] = hi;
    wswl[i] = lo;
  }
  if (i < 2048) {  // zero 64 pad rows of each h buffer (rows NN..NN+63)
    int b = i >> 10, r = (i >> 4) & 63, u = i & 15;
    unsigned short* pad = (b ? hB : hA) + (size_t)(NN + r) * HID;
    *(uint4*)&pad[u * 8] = make_uint4(0u, 0u, 0u, 0u);
  }
}

// ---- exclusive scan (3 kernels) ----
__global__ void k_scan1(const int* __restrict__ deg, int* __restrict__ offs,
                        int* __restrict__ bsum) {
  int i = blockIdx.x * 256 + threadIdx.x;
  int v = (i < NN) ? deg[i] : 0;
  int lane = threadIdx.x & 63, wv = threadIdx.x >> 6;
  int x = v;
  #pragma unroll
  for (int d = 1; d < 64; d <<= 1) {
    int y = __shfl_up(x, d, 64);
    if (lane >= d) x += y;
  }
  __shared__ int wsum[4];
  if (lane == 63) wsum[wv] = x;
  __syncthreads();
  if (threadIdx.x == 0) {
    int s = 0;
    for (int k = 0; k < 4; k++) { int t = wsum[k]; wsum[k] = s; s += t; }
    bsum[blockIdx.x] = s;
  }
  __syncthreads();
  if (i < NN) offs[i] = x - v + wsum[wv];
}

__global__ void k_scan2(int* __restrict__ bsum, int nb) {
  int i = threadIdx.x;
  int v = (i < nb) ? bsum[i] : 0;
  int lane = threadIdx.x & 63, wv = threadIdx.x >> 6;
  int x = v;
  #pragma unroll
  for (int d = 1; d < 64; d <<= 1) {
    int y = __shfl_up(x, d, 64);
    if (lane >= d) x += y;
  }
  __shared__ int wsum[4];
  if (lane == 63) wsum[wv] = x;
  __syncthreads();
  if (threadIdx.x == 0) {
    int s = 0;
    for (int k = 0; k < 4; k++) { int t = wsum[k]; wsum[k] = s; s += t; }
  }
  __syncthreads();
  if (i < nb) bsum[i] = x - v + wsum[wv];
}

__global__ void k_scan3(const int* __restrict__ deg, int* __restrict__ offs,
                        const int* __restrict__ bsum, float* __restrict__ invd) {
  int i = blockIdx.x * 256 + threadIdx.x;
  if (i < NN) {
    offs[i] += bsum[blockIdx.x];
    int d = deg[i];
    invd[i] = 1.0f / (float)(d > 0 ? d : 1);
    if (i == 0) offs[NN] = NE;
  }
}

// ---- CSR fill ----
__global__ void k_fill(const int* __restrict__ src, const int* __restrict__ dst,
                       const int* __restrict__ offs, int* __restrict__ cur,
                       int* __restrict__ csr) {
  int e = blockIdx.x * 256 + threadIdx.x;
  if (e < NE) {
    int d = dst[e];
    int p = atomicAdd(&cur[d], 1);
    csr[offs[d] + p] = src[e];
  }
}

#define ACC8(V) { a0 += bflo(V.x); a1 += bfhi(V.x); a2 += bflo(V.y); \
                  a3 += bfhi(V.y); a4 += bflo(V.z); a5 += bfhi(V.z); \
                  a6 += bflo(V.w); a7 += bfhi(V.w); }

// ---- standalone gather: quarter-wave per node, 24 waves/CU, strip-of-8 ----
__global__ __launch_bounds__(256, 6) void k_agg(const unsigned short* __restrict__ curh,
                                                const int* __restrict__ offs,
                                                const int* __restrict__ csr,
                                                const float* __restrict__ invd,
                                                unsigned short* __restrict__ agg) {
  const int tid = threadIdx.x;
  const int qw = tid >> 4, sl = tid & 15;
  const int node = blockIdx.x * 16 + qw;  // grid = NN/16 exactly
  const unsigned short* rowbase = curh + sl * 8;
  float a0 = 0.f, a1 = 0.f, a2 = 0.f, a3 = 0.f;
  float a4 = 0.f, a5 = 0.f, a6 = 0.f, a7 = 0.f;
  const int s = offs[node], e = offs[node + 1];
  for (int base = s; base < e; base += 16) {
    int idx = (base + sl < e) ? csr[base + sl] : NN;  // pad row NN = zeros
    uint4 v0 = *(const uint4*)(rowbase + (size_t)__shfl(idx, 0, 16) * HID);
    uint4 v1 = *(const uint4*)(rowbase + (size_t)__shfl(idx, 1, 16) * HID);
    uint4 v2 = *(const uint4*)(rowbase + (size_t)__shfl(idx, 2, 16) * HID);
    uint4 v3 = *(const uint4*)(rowbase + (size_t)__shfl(idx, 3, 16) * HID);
    uint4 v4 = *(const uint4*)(rowbase + (size_t)__shfl(idx, 4, 16) * HID);
    uint4 v5 = *(const uint4*)(rowbase + (size_t)__shfl(idx, 5, 16) * HID);
    uint4 v6 = *(const uint4*)(rowbase + (size_t)__shfl(idx, 6, 16) * HID);
    uint4 v7 = *(const uint4*)(rowbase + (size_t)__shfl(idx, 7, 16) * HID);
    ACC8(v0) ACC8(v1) ACC8(v2) ACC8(v3) ACC8(v4) ACC8(v5) ACC8(v6) ACC8(v7)
    if (base + 8 < e) {
      v0 = *(const uint4*)(rowbase + (size_t)__shfl(idx,  8, 16) * HID);
      v1 = *(const uint4*)(rowbase + (size_t)__shfl(idx,  9, 16) * HID);
      v2 = *(const uint4*)(rowbase + (size_t)__shfl(idx, 10, 16) * HID);
      v3 = *(const uint4*)(rowbase + (size_t)__shfl(idx, 11, 16) * HID);
      v4 = *(const uint4*)(rowbase + (size_t)__shfl(idx, 12, 16) * HID);
      v5 = *(const uint4*)(rowbase + (size_t)__shfl(idx, 13, 16) * HID);
      v6 = *(const uint4*)(rowbase + (size_t)__shfl(idx, 14, 16) * HID);
      v7 = *(const uint4*)(rowbase + (size_t)__shfl(idx, 15, 16) * HID);
      ACC8(v0) ACC8(v1) ACC8(v2) ACC8(v3) ACC8(v4) ACC8(v5) ACC8(v6) ACC8(v7)
    }
  }
  float sc = invd[node];
  a0 *= sc; a1 *= sc; a2 *= sc; a3 *= sc;
  a4 *= sc; a5 *= sc; a6 *= sc; a7 *= sc;
  unsigned int w0 = (unsigned int)f2bf(a0) | ((unsigned int)f2bf(a1) << 16);
  unsigned int w1 = (unsigned int)f2bf(a2) | ((unsigned int)f2bf(a3) << 16);
  unsigned int w2 = (unsigned int)f2bf(a4) | ((unsigned int)f2bf(a5) << 16);
  unsigned int w3 = (unsigned int)f2bf(a6) | ((unsigned int)f2bf(a7) << 16);
  *(uint4*)(agg + (size_t)node * HID + sl * 8) = make_uint4(w0, w1, w2, w3);
}

// ---- GEMM: out = relu?( agg@Wl + bl + h@Wr ); A-fragments direct from global ----
__global__ __launch_bounds__(256) void k_gemm(const unsigned short* __restrict__ agg,
                                              const unsigned short* __restrict__ curh,
                                              const unsigned short* __restrict__ wswh,
                                              const unsigned short* __restrict__ wswl,
                                              const float* __restrict__ bias,
                                              unsigned short* __restrict__ out,
                                              int relu) {
  __shared__ __align__(16) unsigned short sW2[8192];  // Whi | Wlo for one chunk
  const int tid = threadIdx.x;
  const int lane = tid & 63, wv = tid >> 6;
  const int row0 = blockIdx.x * 64;
  const int mr = (wv << 4) + (lane & 15);
  const int q = lane >> 4;
  const unsigned short* aRow = agg + (size_t)(row0 + mr) * HID + q * 8;
  const unsigned short* hRow = curh + (size_t)(row0 + mr) * HID + q * 8;

  f32x4 acc[8];
  #pragma unroll
  for (int t = 0; t < 8; t++) acc[t] = (f32x4){0.f, 0.f, 0.f, 0.f};

  for (int c = 0; c < 8; ++c) {
    const uint4* wh = (const uint4*)(wswh + c * 4096);
    const uint4* wl = (const uint4*)(wswl + c * 4096);
    ((uint4*)sW2)[tid] = wh[tid];
    ((uint4*)sW2)[tid + 256] = wh[tid + 256];
    ((uint4*)sW2)[tid + 512] = wl[tid];
    ((uint4*)sW2)[tid + 768] = wl[tid + 256];
    __syncthreads();
    bf16x8 a = *(const bf16x8*)(((c < 4) ? aRow : hRow) + (c & 3) * 32);
    #pragma unroll
    for (int t = 0; t < 8; t++) {
      bf16x8 bh = *(const bf16x8*)&sW2[(t * 4 + q) * 128 + (lane & 15) * 8];
      bf16x8 bl2 = *(const bf16x8*)&sW2[4096 + (t * 4 + q) * 128 + (lane & 15) * 8];
      acc[t] = __builtin_amdgcn_mfma_f32_16x16x32_bf16(a, bh, acc[t], 0, 0, 0);
      acc[t] = __builtin_amdgcn_mfma_f32_16x16x32_bf16(a, bl2, acc[t], 0, 0, 0);
    }
    __syncthreads();
  }

  const int ci = lane & 15;
  const int rb = (wv << 4) + (lane >> 4) * 4;
  #pragma unroll
  for (int t = 0; t < 8; t++) {
    int n = t * 16 + ci;
    float bn = bias[n];
    #pragma unroll
    for (int r2 = 0; r2 < 4; r2++) {
      int row = row0 + rb + r2;
      if (row < NN) {
        float v = acc[t][r2] + bn;
        if (relu) v = fmaxf(v, 0.f);
        out[(size_t)row * HID + n] = f2bf(v);
      }
    }
  }
}

// ---- global add pool (batch sorted -> binary search; 2-row MLP) ----
__global__ void k_pool(const unsigned short* __restrict__ h,
                       const int* __restrict__ batch, float* __restrict__ pooled) {
  int g = blockIdx.x;
  __shared__ int rng[2];
  __shared__ float tmp[HID];
  if (threadIdx.x < 2) {
    int target = g + threadIdx.x;
    int lo = 0, hi = NN;
    while (lo < hi) {
      int mid = (lo + hi) >> 1;
      if (batch[mid] < target) lo = mid + 1; else hi = mid;
    }
    rng[threadIdx.x] = lo;
  }
  __syncthreads();
  int s = rng[0], e = rng[1];
  int f = threadIdx.x & 127, ro = threadIdx.x >> 7;  // 256 threads: 2 row streams
  float a = 0.f;
  for (int r = s + ro; r < e; r += 2) a += bf2f(h[(size_t)r * HID + f]);
  if (ro == 1) tmp[f] = a;
  __syncthreads();
  if (ro == 0) pooled[g * HID + f] = a + tmp[f];
}

// ---- final projection 128 -> 2 (all fp32) ----
__global__ void k_out(const float* __restrict__ pooled,
                      const float* __restrict__ Wout,
                      const float* __restrict__ bout,
                      float* __restrict__ out) {
  int g = blockIdx.x;
  int l = threadIdx.x;  // 64
  float a = pooled[g * HID + l], b = pooled[g * HID + 64 + l];
  float p0 = a * Wout[l * 2] + b * Wout[(l + 64) * 2];
  float p1 = a * Wout[l * 2 + 1] + b * Wout[(l + 64) * 2 + 1];
  #pragma unroll
  for (int d = 32; d; d >>= 1) {
    p0 += __shfl_down(p0, d, 64);
    p1 += __shfl_down(p1, d, 64);
  }
  if (l == 0) {
    out[g * 2] = p0 + bout[0];
    out[g * 2 + 1] = p1 + bout[1];
  }
}

extern "C" void kernel_launch(void* const* d_in, const int* in_sizes, int n_in,
                              void* d_out, int out_size, void* d_ws, size_t ws_size,
                              hipStream_t stream) {
  const float* x = (const float*)d_in[0];
  const int* ei = (const int*)d_in[1];
  const int* batch = (const int*)d_in[2];
  const float* Wl = (const float*)d_in[3];
  const float* Wr = (const float*)d_in[4];
  const float* bl = (const float*)d_in[5];
  const float* Wout = (const float*)d_in[6];
  const float* bout = (const float*)d_in[7];
  float* out = (float*)d_out;
  const int* srcE = ei;
  const int* dstE = ei + NE;

  // workspace layout (~43 MB); h buffers padded to NN+64 rows (zeroed)
  char* w = (char*)d_ws;
  unsigned short* hA = (unsigned short*)w;  w += (size_t)(NN + 64) * HID * 2;
  unsigned short* hB = (unsigned short*)w;  w += (size_t)(NN + 64) * HID * 2;
  unsigned short* agg = (unsigned short*)w; w += (size_t)(NN + 64) * HID * 2;
  float* invd = (float*)w;   w += (size_t)NN * 4;
  float* pooled = (float*)w; w += (size_t)NG * HID * 4;
  int* deg = (int*)w;  w += (size_t)NN * 4;
  int* cur = (int*)w;  w += (size_t)NN * 4;      // adjacent to deg (one memset)
  int* offs = (int*)w; w += (size_t)50004 * 4;
  int* csr = (int*)w;  w += (size_t)NE * 4;
  int* bsum = (int*)w; w += 256 * 4;
  unsigned short* wswh = (unsigned short*)w; w += (size_t)NL * 2 * 4 * 4096 * 2;
  unsigned short* wswl = (unsigned short*)w;

  hipMemsetAsync(deg, 0, (size_t)NN * 2 * 4, stream);
  k_pre<<<(NN * HID / 4 + 255) / 256, 256, 0, stream>>>(x, hA, hB, dstE, deg,
                                                        Wl, Wr, wswh, wswl);
  int nb = (NN + 255) / 256;
  k_scan1<<<nb, 256, 0, stream>>>(deg, offs, bsum);
  k_scan2<<<1, 256, 0, stream>>>(bsum, nb);
  k_scan3<<<nb, 256, 0, stream>>>(deg, offs, bsum, invd);
  k_fill<<<(NE + 255) / 256, 256, 0, stream>>>(srcE, dstE, offs, cur, csr);

  unsigned short* curh = hA;
  unsigned short* nxth = hB;
  for (int l = 0; l < NL; l++) {
    k_agg<<<NN / 16, 256, 0, stream>>>(curh, offs, csr, invd, agg);
    k_gemm<<<(NN + 63) / 64, 256, 0, stream>>>(agg, curh,
                                               wswh + (size_t)l * 2 * 4 * 4096,
                                               wswl + (size_t)l * 2 * 4 * 4096,
                                               bl + l * HID, nxth,
                                               (l < NL - 1) ? 1 : 0);
    unsigned short* t = curh; curh = nxth; nxth = t;
  }
  k_pool<<<NG, 256, 0, stream>>>(curh, batch, pooled);
  k_out<<<NG, 64, 0, stream>>>(pooled, Wout, bout, out);
}